// Round 2
// baseline (524.469 us; speedup 1.0000x reference)
//
#include <hip/hip_runtime.h>
#include <hip/hip_bf16.h>
#include <stdint.h>

#define WW    361    // W*W spatial positions
#define CCH   64     // channels (K)
#define MH    192    // support rows per job (i-half)
#define QC    96     // query rows per chunk (6 tiles of 16)
#define NPQ   384    // 4 chunks of 96 (rows 361..383 staged as zeros)
#define NJOBS 1200   // B*S*2 halves
#define NTHR  768    // 12 waves: 1 i-tile per wave
#define GRID  512    // 2 blocks/CU co-resident
#define WWC   (WW*CCH)

typedef __attribute__((ext_vector_type(8))) short short8;
typedef __attribute__((ext_vector_type(8))) float f32x8;
typedef __attribute__((ext_vector_type(4))) float f32x4;

// LDS layout per row: pitch 64 bf16 (128B), 16B-chunk XOR swizzle:
// element (m,k) at m*64 + ((k/8 ^ (m&7))*8) + (k&7). Bank-uniform for b128
// stores and b128 fragment reads (proven R1/R2 of prior session).
//
// R2 structure: q-chunked LDS (4 chunks/job, 3 rotating 12KB buffers),
// S single-buffered (dead after job-start A-frag reg load -> next job's S
// overwrites mid-job). 63KB LDS -> 2 blocks/CU (24 waves TLP) AND 2-chunk
// load-ahead (~1000cy cover > ~900cy HBM latency). Dynamic job stealing
// via atomic counter in d_ws (memset each replay).

// issue 8 strided floats for one row-octant into registers (coalesced across
// the 8 lanes of a row-group; zero if row is padding)
__device__ __forceinline__ void stage_issue(f32x8& f, const float* __restrict__ base,
                                            int row, bool v, int c8) {
  if (v) {
    const float* p = base + row + c8 * 8 * WW;
    #pragma unroll
    for (int j = 0; j < 8; ++j) f[j] = p[j * WW];
  } else {
    #pragma unroll
    for (int j = 0; j < 8; ++j) f[j] = 0.f;
  }
}

// convert 8 f32 -> bf16x8, write one swizzled 16B granule, 8-lane-reduce the
// sum of squares, leader lane writes inv (rsqrt) or 0 for pad rows.
__device__ __forceinline__ void stage_write(const f32x8& f, unsigned short* __restrict__ rowdst,
                                            float* __restrict__ invdst, bool vrow,
                                            int lr, int c8) {
  unsigned int u[4];
  float a0 = 0.f, a1 = 0.f;
  #pragma unroll
  for (int jj = 0; jj < 4; ++jj) {
    float x = f[2*jj], y = f[2*jj + 1];
    a0 += x * x; a1 += y * y;
    __hip_bfloat162 b2 = __float22bfloat162_rn(make_float2(x, y));
    u[jj] = *(unsigned int*)&b2;
  }
  float ss = a0 + a1;
  ss += __shfl_xor(ss, 1);
  ss += __shfl_xor(ss, 2);
  ss += __shfl_xor(ss, 4);
  *(uint4*)&rowdst[((c8 ^ (lr & 7)) * 8)] = make_uint4(u[0], u[1], u[2], u[3]);
  if (c8 == 0) invdst[0] = vrow ? rsqrtf(ss) : 0.f;
}

__device__ __forceinline__ void chunk_compute(const unsigned short* __restrict__ Qb,
                                              const float* __restrict__ iqb,
                                              short8 af0, short8 af1,
                                              int boff0, int boff1, int l15,
                                              f32x4& mx, float b4, float b5) {
  #pragma unroll
  for (int ptL = 0; ptL < 6; ++ptL) {
    const int nb = ptL * 16 * CCH;
    short8 b0 = *(const short8*)&Qb[nb + boff0];
    short8 b1 = *(const short8*)&Qb[nb + boff1];
    const float qs = iqb[ptL * 16 + l15];
    f32x4 acc = {0.f, 0.f, 0.f, 0.f};
    acc = __builtin_amdgcn_mfma_f32_16x16x32_bf16(af0, b0, acc, 0, 0, 0);
    acc = __builtin_amdgcn_mfma_f32_16x16x32_bf16(af1, b1, acc, 0, 0, 0);
    const float bb = (ptL == 4) ? b4 : ((ptL == 5) ? b5 : 0.f);
    #pragma unroll
    for (int r = 0; r < 4; ++r) mx[r] = fmaxf(mx[r], acc[r] * qs + bb);
  }
}

__global__ __launch_bounds__(NTHR, 6) void cossim_max_kernel(
    const float* __restrict__ support, const float* __restrict__ query,
    float* __restrict__ out, unsigned int* __restrict__ ctr)
{
  __shared__ __align__(16) unsigned short S_sh[MH * CCH];     // 24576 B
  __shared__ __align__(16) unsigned short Q_sh[3][QC * CCH];  // 36864 B
  __shared__ float inv_s[MH];                                 //   768 B
  __shared__ float inv_q[3][QC];                              //  1152 B
  __shared__ int jslot;                                       // ~63.4 KB total

  const int tid  = threadIdx.x;
  const int r    = tid >> 3;    // staging row 0..95 (8 threads/row)
  const int c8   = tid & 7;     // 8-float octant within the row
  const int lane = tid & 63;
  const int wv   = tid >> 6;    // i-tile owner
  const int l15  = lane & 15;
  const int quad = lane >> 4;
  const int bsw  = l15 & 7;
  const float lastbias4 = (l15 < 9) ? 0.f : -1e30f;  // global tile 22: n=352+l15

  const int am    = 16 * wv + l15;
  const int aoff0 = am * CCH + (((0 + quad) ^ (am & 7)) * 8);
  const int aoff1 = am * CCH + (((4 + quad) ^ (am & 7)) * 8);
  const int boff0 = l15 * CCH + (((0 + quad) ^ bsw) * 8);
  const int boff1 = l15 * CCH + (((4 + quad) ^ bsw) * 8);

  int j  = blockIdx.x;          // first job is static (GRID <= NJOBS)
  int bs = j >> 1;
  int mBase = (j & 1) * MH;
  const float* qbase = query   + (size_t)bs * WWC;
  const float* sbase = support + (size_t)bs * WWC;

  // ---- prologue: stage S (both 96-row halves) + Q chunk0, exposed once ----
  {
    f32x8 s0, s1, q0;
    stage_issue(s0, sbase, mBase + r,      (mBase + r) < WW,      c8);
    stage_issue(s1, sbase, mBase + 96 + r, (mBase + 96 + r) < WW, c8);
    stage_issue(q0, qbase, r,              true,                  c8);
    stage_write(s0, &S_sh[r * CCH],        &inv_s[r],      (mBase + r) < WW,      r, c8);
    stage_write(s1, &S_sh[(96 + r) * CCH], &inv_s[96 + r], (mBase + 96 + r) < WW, r, c8);
    stage_write(q0, &Q_sh[0][r * CCH],     &inv_q[0][r],   true,                  r, c8);
    __syncthreads();
  }

  short8 af0 = *(const short8*)&S_sh[aoff0];
  short8 af1 = *(const short8*)&S_sh[aoff1];
  float  invA = inv_s[am];      // snapshot: LDS inv_s is overwritten mid-job
  f32x4  mx = {-3e38f, -3e38f, -3e38f, -3e38f};

  f32x8 qfA, qfB, sf;
  stage_issue(qfA, qbase, QC + r, true, c8);   // chunk1 in flight
  int ib = 0;

  int jn = 0; bool vn = false;
  int mBase_n = 0;
  const float* qbase_n = query;
  const float* sbase_n = support;

  for (;;) {
    // ==== qc0: grab next job; issue chunk2; compute chunk0; write chunk1 ====
    if (tid == 0) jslot = (int)(GRID + atomicAdd(ctr, 1u));
    stage_issue(qfB, qbase, 2 * QC + r, true, c8);
    chunk_compute(&Q_sh[ib][0], &inv_q[ib][0], af0, af1, boff0, boff1, l15, mx, 0.f, 0.f);
    {
      int ibw = ib + 1; if (ibw == 3) ibw = 0;
      stage_write(qfA, &Q_sh[ibw][r * CCH], &inv_q[ibw][r], true, r, c8);
    }
    __syncthreads();
    {
      int js = jslot;
      jn = __builtin_amdgcn_readfirstlane(js);
      vn = (jn < NJOBS);
      int bsn = vn ? (jn >> 1) : 0;
      mBase_n = (jn & 1) * MH;
      qbase_n = query   + (size_t)bsn * WWC;
      sbase_n = support + (size_t)bsn * WWC;
    }
    ib = (ib + 1 == 3) ? 0 : ib + 1;

    // ==== qc1: issue chunk3 + S(jn) half0; compute chunk1; write chunk2 ====
    stage_issue(qfA, qbase, 3 * QC + r, (3 * QC + r) < WW, c8);
    if (vn) stage_issue(sf, sbase_n, mBase_n + r, (mBase_n + r) < WW, c8);
    chunk_compute(&Q_sh[ib][0], &inv_q[ib][0], af0, af1, boff0, boff1, l15, mx, 0.f, 0.f);
    {
      int ibw = ib + 1; if (ibw == 3) ibw = 0;
      stage_write(qfB, &Q_sh[ibw][r * CCH], &inv_q[ibw][r], true, r, c8);
    }
    __syncthreads();
    ib = (ib + 1 == 3) ? 0 : ib + 1;

    // ==== qc2: issue Q0(jn); compute chunk2; write chunk3 + S half0; issue S half1 ====
    if (vn) stage_issue(qfB, qbase_n, r, true, c8);
    chunk_compute(&Q_sh[ib][0], &inv_q[ib][0], af0, af1, boff0, boff1, l15, mx, 0.f, 0.f);
    {
      int ibw = ib + 1; if (ibw == 3) ibw = 0;
      stage_write(qfA, &Q_sh[ibw][r * CCH], &inv_q[ibw][r], (3 * QC + r) < WW, r, c8);
    }
    if (vn) {
      stage_write(sf, &S_sh[r * CCH], &inv_s[r], (mBase_n + r) < WW, r, c8);
      stage_issue(sf, sbase_n, mBase_n + 96 + r, (mBase_n + 96 + r) < WW, c8);
    }
    __syncthreads();
    ib = (ib + 1 == 3) ? 0 : ib + 1;

    // ==== qc3: issue Q1(jn); compute chunk3 (biased); epilogue; write Q0(jn)+S half1 ====
    if (vn) stage_issue(qfA, qbase_n, QC + r, true, c8);
    chunk_compute(&Q_sh[ib][0], &inv_q[ib][0], af0, af1, boff0, boff1, l15, mx,
                  lastbias4, -1e30f);
    // max over columns (C layout: col = lane&15): butterfly in 16-lane group
    #pragma unroll
    for (int d = 1; d < 16; d <<= 1) {
      #pragma unroll
      for (int rr = 0; rr < 4; ++rr) mx[rr] = fmaxf(mx[rr], __shfl_xor(mx[rr], d));
    }
    {
      const float iv0 = __shfl(invA, 4 * quad + 0);
      const float iv1 = __shfl(invA, 4 * quad + 1);
      const float iv2 = __shfl(invA, 4 * quad + 2);
      const float iv3 = __shfl(invA, 4 * quad + 3);
      if (l15 == 0) {
        const size_t ob = (size_t)bs * WW;
        const int mL = 16 * wv + 4 * quad;
        if (mBase + mL + 0 < WW) out[ob + mBase + mL + 0] = mx[0] * iv0;
        if (mBase + mL + 1 < WW) out[ob + mBase + mL + 1] = mx[1] * iv1;
        if (mBase + mL + 2 < WW) out[ob + mBase + mL + 2] = mx[2] * iv2;
        if (mBase + mL + 3 < WW) out[ob + mBase + mL + 3] = mx[3] * iv3;
      }
    }
    {
      int ibw = ib + 1; if (ibw == 3) ibw = 0;
      if (vn) stage_write(qfB, &Q_sh[ibw][r * CCH], &inv_q[ibw][r], true, r, c8);
    }
    if (vn) stage_write(sf, &S_sh[(96 + r) * CCH], &inv_s[96 + r],
                        (mBase_n + 96 + r) < WW, r, c8);
    __syncthreads();
    if (!vn) break;

    // advance to next job (its S + Q chunk0 are staged, Q chunk1 in flight)
    j = jn; bs = jn >> 1; mBase = mBase_n; qbase = qbase_n; sbase = sbase_n;
    af0 = *(const short8*)&S_sh[aoff0];
    af1 = *(const short8*)&S_sh[aoff1];
    invA = inv_s[am];
    mx[0] = -3e38f; mx[1] = -3e38f; mx[2] = -3e38f; mx[3] = -3e38f;
    ib = (ib + 1 == 3) ? 0 : ib + 1;
  }
}

extern "C" void kernel_launch(void* const* d_in, const int* in_sizes, int n_in,
                              void* d_out, int out_size, void* d_ws, size_t ws_size,
                              hipStream_t stream) {
  const float* support = (const float*)d_in[0];
  const float* query   = (const float*)d_in[1];
  float* out = (float*)d_out;
  unsigned int* ctr = (unsigned int*)d_ws;
  hipMemsetAsync(ctr, 0, sizeof(unsigned int), stream);  // reset per replay
  dim3 grid(GRID), block(NTHR);
  hipLaunchKernelGGL(cossim_max_kernel, grid, block, 0, stream,
                     support, query, out, ctr);
}

// Round 4
// 249.980 us; speedup vs baseline: 2.0980x; 2.0980x over previous
//
#include <hip/hip_runtime.h>
#include <hip/hip_bf16.h>
#include <stdint.h>

#define WW    361    // W*W spatial positions
#define CCH   64     // channels (K)
#define MH    192    // support rows per job (i-half)
#define QCH   192    // query rows per chunk (2 chunks/job, 12 tiles each)
#define NJOBS 1200   // B*S*2 halves
#define NTHR  768    // 12 waves: 1 i-tile per wave
#define GRID  512    // persistent, 2 blocks/CU
#define WWC   (WW*CCH)

typedef __attribute__((ext_vector_type(8))) short short8;
typedef __attribute__((ext_vector_type(4))) float f32x4;

// LDS: ONLY a 3-slot ring of 192-row Q chunks (bf16, swizzled) + their inv-norms.
// S never touches LDS: each wave gathers its own A-fragment rows from global.
// Per row: pitch 64 bf16 (128B), 16B-granule XOR swizzle (g ^ (row&7)) --
// proven bank-uniform for b128 stores and b128 fragment reads.
//
// Pipeline (2 phases/job, 1 barrier/phase, ring-3 so pre-barrier writes can
// never clobber a slot that laggard waves still read):
//   phase0: write c1(t); bar; issue c0(t+1); build af(t); compute c0(t); convert
//   phase1: write c0(t+1); bar; issue c1(t+1)+af(t+1); compute c1(t); epilogue; convert
// Payload across barriers = 2*uint4 + float (9 VGPR). Barriers are manual
// lgkmcnt(0)+s_barrier so in-flight global loads survive the barrier.

__device__ __forceinline__ void blockbar() {
  asm volatile("s_waitcnt lgkmcnt(0)" ::: "memory");
  __builtin_amdgcn_s_barrier();
  __builtin_amdgcn_sched_barrier(0);
}

// issue 16 strided floats (channels 16*c16 .. 16*c16+15 of one q-row)
__device__ __forceinline__ void issue16(float* v, const float* __restrict__ p,
                                        bool valid, int c16) {
  if (valid) {
    #pragma unroll
    for (int j = 0; j < 16; ++j) v[j] = p[(c16 * 16 + j) * WW];
  } else {
    #pragma unroll
    for (int j = 0; j < 16; ++j) v[j] = 0.f;
  }
}

// convert 16 f32 -> 2 swizzle-granules of bf16, reduce row sumsq over the
// 4 partner lanes (same row), produce inv = rsqrt or 0 for pad rows.
__device__ __forceinline__ void conv16(const float* v, uint4& g0, uint4& g1,
                                       float& inv, bool validrow) {
  unsigned int u[8];
  float ss = 0.f;
  #pragma unroll
  for (int jj = 0; jj < 8; ++jj) {
    float x = v[2 * jj], y = v[2 * jj + 1];
    ss += x * x + y * y;
    __hip_bfloat162 b2 = __float22bfloat162_rn(make_float2(x, y));
    u[jj] = *(unsigned int*)&b2;
  }
  ss += __shfl_xor(ss, 1);
  ss += __shfl_xor(ss, 2);
  g0 = make_uint4(u[0], u[1], u[2], u[3]);
  g1 = make_uint4(u[4], u[5], u[6], u[7]);
  inv = validrow ? rsqrtf(ss) : 0.f;
}

__device__ __forceinline__ void writeP(unsigned short* __restrict__ dst,
                                       float* __restrict__ invdst,
                                       uint4 g0, uint4 g1, float inv,
                                       int r, int c16) {
  const int ga = (2 * c16)     ^ (r & 7);
  const int gb = (2 * c16 + 1) ^ (r & 7);
  *(uint4*)&dst[ga * 8] = g0;
  *(uint4*)&dst[gb * 8] = g1;
  if (c16 == 0) invdst[0] = inv;
}

// gather one wave's A-fragment row (16 channels for this lane) from global
__device__ __forceinline__ void issueAF(float* w, const float* __restrict__ srow,
                                        bool valid, int quad) {
  if (valid) {
    #pragma unroll
    for (int j = 0; j < 8; ++j) w[j]     = srow[(8 * quad + j) * WW];
    #pragma unroll
    for (int j = 0; j < 8; ++j) w[8 + j] = srow[(32 + 8 * quad + j) * WW];
  } else {
    #pragma unroll
    for (int j = 0; j < 16; ++j) w[j] = 0.f;
  }
}

// convert gathered A floats -> fragments; row sumsq reduced across the 4 quads
__device__ __forceinline__ void afbuild(const float* w, bool valid,
                                        short8& af0, short8& af1, float& invA) {
  unsigned int u[8];
  float ss = 0.f;
  #pragma unroll
  for (int jj = 0; jj < 8; ++jj) {
    float x = w[2 * jj], y = w[2 * jj + 1];
    ss += x * x + y * y;
    __hip_bfloat162 b2 = __float22bfloat162_rn(make_float2(x, y));
    u[jj] = *(unsigned int*)&b2;
  }
  ss += __shfl_xor(ss, 16);
  ss += __shfl_xor(ss, 32);
  uint4 t0 = make_uint4(u[0], u[1], u[2], u[3]);
  uint4 t1 = make_uint4(u[4], u[5], u[6], u[7]);
  af0 = *(short8*)&t0;
  af1 = *(short8*)&t1;
  invA = valid ? rsqrtf(ss) : 0.f;
}

template<int NTILES, bool BIAS>
__device__ __forceinline__ void chunkCompute(const unsigned short* __restrict__ Qb,
                                             const float* __restrict__ iqb,
                                             short8 af0, short8 af1,
                                             int boff0, int boff1, int l15,
                                             float lastbias, f32x4& mx) {
  #pragma unroll
  for (int t = 0; t < NTILES; ++t) {
    const int nb = t * 16 * CCH;
    short8 b0 = *(const short8*)&Qb[nb + boff0];
    short8 b1 = *(const short8*)&Qb[nb + boff1];
    const float qs = iqb[t * 16 + l15];
    f32x4 acc = {0.f, 0.f, 0.f, 0.f};
    __builtin_amdgcn_s_setprio(1);
    acc = __builtin_amdgcn_mfma_f32_16x16x32_bf16(af0, b0, acc, 0, 0, 0);
    acc = __builtin_amdgcn_mfma_f32_16x16x32_bf16(af1, b1, acc, 0, 0, 0);
    __builtin_amdgcn_s_setprio(0);
    const float bb = (BIAS && t == NTILES - 1) ? lastbias : 0.f;
    #pragma unroll
    for (int r = 0; r < 4; ++r) mx[r] = fmaxf(mx[r], acc[r] * qs + bb);
  }
}

__global__ __launch_bounds__(NTHR, 6) void cossim_max_kernel(
    const float* __restrict__ support, const float* __restrict__ query,
    float* __restrict__ out, unsigned int* __restrict__ ctr)
{
  __shared__ __align__(16) unsigned short Qr[3][QCH * CCH];  // 73728 B
  __shared__ float iQr[3][QCH];                              //  2304 B
  __shared__ int jslot;                                      // ~76 KB total

  const int tid  = threadIdx.x;
  const int lane = tid & 63;
  const int wv   = tid >> 6;     // 0..11 -> i-tile
  const int l15  = lane & 15;
  const int quad = lane >> 4;

  const int r   = tid >> 2;      // staging row 0..191 (4 threads/row)
  const int c16 = tid & 3;       // 16-channel quarter

  const int am    = 16 * wv + l15;
  const int boff0 = l15 * CCH + ((quad       ^ (l15 & 7)) * 8);
  const int boff1 = l15 * CCH + (((4 + quad) ^ (l15 & 7)) * 8);
  const float lastbias = (l15 < 9) ? 0.f : -1e30f;  // tile 22: n = 352+l15

  int jcur  = blockIdx.x;        // first job static (GRID <= NJOBS)
  int bs    = jcur >> 1;
  int mBase = (jcur & 1) * MH;
  const float* qb = query   + (size_t)bs * WWC;
  const float* sb = support + (size_t)bs * WWC;

  int s0 = 0, s1 = 1, s2 = 2;    // ring slots: c0(t), c1(t), c0(t+1)

  float wA[16];                  // in-flight A gather (issued 1 phase early)
  uint4 pg0, pg1; float pinv;    // staged-chunk payload across a barrier

  // ---- prologue: direct-stage c0(j0); put c1(j0) + af(j0) in flight ----
  {
    float v0[16];
    issue16(v0, qb + r, true, c16);                 // rows 0..191 all valid
    uint4 g0, g1; float inv;
    conv16(v0, g0, g1, inv, true);
    writeP(&Qr[0][r * CCH], &iQr[0][r], g0, g1, inv, r, c16);
    float v1[16];
    issue16(v1, qb + 192 + r, (192 + r) < WW, c16); // c1(j0)
    issueAF(wA, sb + mBase + am, (mBase + am) < WW, quad);
    blockbar();
    conv16(v1, pg0, pg1, pinv, (192 + r) < WW);     // af stays in flight
  }

  for (;;) {
    // ================= phase 0: compute c0(t) =================
    if (tid == 0) jslot = (int)(GRID + atomicAdd(ctr, 1u));
    writeP(&Qr[s1][r * CCH], &iQr[s1][r], pg0, pg1, pinv, r, c16);  // c1(t)
    blockbar();
    const int  jn = __builtin_amdgcn_readfirstlane(jslot);
    const bool vn = jn < NJOBS;
    const int  bsn = vn ? (jn >> 1) : 0;
    const int  mBn = (jn & 1) * MH;
    const float* qbn = query   + (size_t)bsn * WWC;
    const float* sbn = support + (size_t)bsn * WWC;

    float vq[16];
    if (vn) issue16(vq, qbn + r, true, c16);        // c0(t+1) in flight
    short8 af0, af1; float invA;
    afbuild(wA, (mBase + am) < WW, af0, af1, invA); // waits wA only (counted)
    f32x4 mx = {-3e38f, -3e38f, -3e38f, -3e38f};
    chunkCompute<12, false>(&Qr[s0][0], &iQr[s0][0], af0, af1,
                            boff0, boff1, l15, 0.f, mx);
    if (vn) conv16(vq, pg0, pg1, pinv, true);

    // ================= phase 1: compute c1(t) =================
    if (vn) writeP(&Qr[s2][r * CCH], &iQr[s2][r], pg0, pg1, pinv, r, c16);
    blockbar();
    float vq2[16];
    if (vn) {
      issue16(vq2, qbn + 192 + r, (192 + r) < WW, c16);  // c1(t+1)
      issueAF(wA, sbn + mBn + am, (mBn + am) < WW, quad); // af(t+1)
    }
    chunkCompute<11, true>(&Qr[s1][0], &iQr[s1][0], af0, af1,
                           boff0, boff1, l15, lastbias, mx);

    // epilogue: max over columns (C layout: col = lane&15), then store
    #pragma unroll
    for (int d = 1; d < 16; d <<= 1) {
      #pragma unroll
      for (int rr = 0; rr < 4; ++rr) mx[rr] = fmaxf(mx[rr], __shfl_xor(mx[rr], d));
    }
    {
      const float iv0 = __shfl(invA, 4 * quad + 0);
      const float iv1 = __shfl(invA, 4 * quad + 1);
      const float iv2 = __shfl(invA, 4 * quad + 2);
      const float iv3 = __shfl(invA, 4 * quad + 3);
      if (l15 == 0) {
        const size_t ob = (size_t)bs * WW;
        const int mL = 16 * wv + 4 * quad;
        if (mBase + mL + 0 < WW) out[ob + mBase + mL + 0] = mx[0] * iv0;
        if (mBase + mL + 1 < WW) out[ob + mBase + mL + 1] = mx[1] * iv1;
        if (mBase + mL + 2 < WW) out[ob + mBase + mL + 2] = mx[2] * iv2;
        if (mBase + mL + 3 < WW) out[ob + mBase + mL + 3] = mx[3] * iv3;
      }
    }

    if (!vn) break;
    conv16(vq2, pg0, pg1, pinv, (192 + r) < WW);    // af(t+1) stays in flight

    // advance to next job; ring rotates by 2 (c0(t+1) already sits in s2)
    jcur = jn; bs = bsn; mBase = mBn; qb = qbn; sb = sbn;
    const int ns0 = s2, ns1 = s0, ns2 = s1;
    s0 = ns0; s1 = ns1; s2 = ns2;
  }
}

extern "C" void kernel_launch(void* const* d_in, const int* in_sizes, int n_in,
                              void* d_out, int out_size, void* d_ws, size_t ws_size,
                              hipStream_t stream) {
  const float* support = (const float*)d_in[0];
  const float* query   = (const float*)d_in[1];
  float* out = (float*)d_out;
  unsigned int* ctr = (unsigned int*)d_ws;
  hipMemsetAsync(ctr, 0, sizeof(unsigned int), stream);  // reset per replay
  dim3 grid(GRID), block(NTHR);
  hipLaunchKernelGGL(cossim_max_kernel, grid, block, 0, stream,
                     support, query, out, ctr);
}

// Round 5
// 195.706 us; speedup vs baseline: 2.6799x; 1.2773x over previous
//
#include <hip/hip_runtime.h>
#include <hip/hip_bf16.h>
#include <stdint.h>

#define WW    361    // W*W spatial positions
#define CCH   64     // channels (K)
#define MH    128    // support rows per job (8 i-tiles, 1 per wave)
#define QCH   128    // query rows per chunk; 3 chunks cover 361 (+pad)
#define NJOBS 1800   // 600 bs x 3 thirds
#define NTHR  512    // 8 waves
#define GRID  512    // persistent, 2 blocks/CU
#define WWC   (WW*CCH)

typedef __attribute__((ext_vector_type(8))) short short8;
typedef __attribute__((ext_vector_type(4))) float f32x4;

// R5: same pipeline as R3/R4 (3-slot Q ring, per-wave A-gather, counted-wait
// barriers, job stealing) resized to the 128-VGPR operating point:
// 8-wave blocks, __launch_bounds__(512,4) -> cap 128 VGPR (R2/R4 spilled at
// the 85-cap of (768,6): WRITE_SIZE 345MB scratch). 2 blocks/CU, 16 waves/CU.
//
// Slots are STATICALLY bound (Qr[0]=c0, Qr[1]=c1, Qr[2]=c2): with 3 chunks
// and 3 phases, each slot-write lands 2 phases after that slot's last read,
// so a write at phase-start can never race a laggard reader (all readers
// retired by the preceding barrier).
//
// LDS row layout: pitch 64 bf16 (128B), 16B-granule XOR swizzle (g ^ (r&7)).
// Bank-uniform for b128 writes and b128 fragment reads (proven R1/R2).

__device__ __forceinline__ void blockbar() {
  asm volatile("s_waitcnt lgkmcnt(0)" ::: "memory");
  __builtin_amdgcn_s_barrier();
  __builtin_amdgcn_sched_barrier(0);
}

// issue 16 strided floats (channels 16*c16 .. 16*c16+15 of one q-row)
__device__ __forceinline__ void issue16(float* v, const float* __restrict__ p,
                                        bool valid, int c16) {
  if (valid) {
    #pragma unroll
    for (int j = 0; j < 16; ++j) v[j] = p[(c16 * 16 + j) * WW];
  } else {
    #pragma unroll
    for (int j = 0; j < 16; ++j) v[j] = 0.f;
  }
}

// convert 16 f32 -> 2 swizzle granules; reduce row sumsq over the 4 partner
// lanes (tid bits 0-1 = c16); inv = rsqrt or 0 for pad rows.
__device__ __forceinline__ void conv16(const float* v, uint4& g0, uint4& g1,
                                       float& inv, bool validrow) {
  unsigned int u[8];
  float ss = 0.f;
  #pragma unroll
  for (int jj = 0; jj < 8; ++jj) {
    float x = v[2 * jj], y = v[2 * jj + 1];
    ss += x * x + y * y;
    __hip_bfloat162 b2 = __float22bfloat162_rn(make_float2(x, y));
    u[jj] = *(unsigned int*)&b2;
  }
  ss += __shfl_xor(ss, 1);
  ss += __shfl_xor(ss, 2);
  g0 = make_uint4(u[0], u[1], u[2], u[3]);
  g1 = make_uint4(u[4], u[5], u[6], u[7]);
  inv = validrow ? rsqrtf(ss) : 0.f;
}

__device__ __forceinline__ void writeP(unsigned short* __restrict__ dst,
                                       float* __restrict__ invdst,
                                       uint4 g0, uint4 g1, float inv,
                                       int r, int c16) {
  const int ga = (2 * c16)     ^ (r & 7);
  const int gb = (2 * c16 + 1) ^ (r & 7);
  *(uint4*)&dst[ga * 8] = g0;
  *(uint4*)&dst[gb * 8] = g1;
  if (c16 == 0) invdst[0] = inv;
}

// gather one wave's A-fragment row (16 channels for this lane) from global
__device__ __forceinline__ void issueAF(float* w, const float* __restrict__ srow,
                                        bool valid, int quad) {
  if (valid) {
    #pragma unroll
    for (int j = 0; j < 8; ++j) w[j]     = srow[(8 * quad + j) * WW];
    #pragma unroll
    for (int j = 0; j < 8; ++j) w[8 + j] = srow[(32 + 8 * quad + j) * WW];
  } else {
    #pragma unroll
    for (int j = 0; j < 16; ++j) w[j] = 0.f;
  }
}

// convert gathered A floats -> fragments; row sumsq reduced across the 4 quads
__device__ __forceinline__ void afbuild(const float* w, bool valid,
                                        short8& af0, short8& af1, float& invA) {
  unsigned int u[8];
  float ss = 0.f;
  #pragma unroll
  for (int jj = 0; jj < 8; ++jj) {
    float x = w[2 * jj], y = w[2 * jj + 1];
    ss += x * x + y * y;
    __hip_bfloat162 b2 = __float22bfloat162_rn(make_float2(x, y));
    u[jj] = *(unsigned int*)&b2;
  }
  ss += __shfl_xor(ss, 16);
  ss += __shfl_xor(ss, 32);
  uint4 t0 = make_uint4(u[0], u[1], u[2], u[3]);
  uint4 t1 = make_uint4(u[4], u[5], u[6], u[7]);
  af0 = *(short8*)&t0;
  af1 = *(short8*)&t1;
  invA = valid ? rsqrtf(ss) : 0.f;
}

template<int NTILES, bool BIAS>
__device__ __forceinline__ void chunkCompute(const unsigned short* __restrict__ Qb,
                                             const float* __restrict__ iqb,
                                             short8 af0, short8 af1,
                                             int boff0, int boff1, int l15,
                                             float lastbias, f32x4& mx) {
  #pragma unroll
  for (int t = 0; t < NTILES; ++t) {
    const int nb = t * 16 * CCH;
    short8 b0 = *(const short8*)&Qb[nb + boff0];
    short8 b1 = *(const short8*)&Qb[nb + boff1];
    const float qs = iqb[t * 16 + l15];
    f32x4 acc = {0.f, 0.f, 0.f, 0.f};
    __builtin_amdgcn_s_setprio(1);
    acc = __builtin_amdgcn_mfma_f32_16x16x32_bf16(af0, b0, acc, 0, 0, 0);
    acc = __builtin_amdgcn_mfma_f32_16x16x32_bf16(af1, b1, acc, 0, 0, 0);
    __builtin_amdgcn_s_setprio(0);
    const float bb = (BIAS && t == NTILES - 1) ? lastbias : 0.f;
    #pragma unroll
    for (int r = 0; r < 4; ++r) mx[r] = fmaxf(mx[r], acc[r] * qs + bb);
  }
}

__global__ __launch_bounds__(NTHR, 4) void cossim_max_kernel(
    const float* __restrict__ support, const float* __restrict__ query,
    float* __restrict__ out, unsigned int* __restrict__ ctr)
{
  __shared__ __align__(16) unsigned short Qr[3][QCH * CCH];  // 49152 B
  __shared__ float iQr[3][QCH];                              //  1536 B
  __shared__ int jslot;                                      // ~50 KB total

  const int tid  = threadIdx.x;
  const int lane = tid & 63;
  const int wv   = tid >> 6;     // 0..7 -> i-tile
  const int l15  = lane & 15;
  const int quad = lane >> 4;

  const int r   = tid >> 2;      // staging row 0..127 (4 threads/row)
  const int c16 = tid & 3;       // 16-channel quarter

  const int am    = 16 * wv + l15;                 // 0..127
  const int boff0 = l15 * CCH + ((quad       ^ (l15 & 7)) * 8);
  const int boff1 = l15 * CCH + (((4 + quad) ^ (l15 & 7)) * 8);
  // chunk2 tile6 covers global q-rows 352..367: col n = 352 + l15
  const float lastbias = (l15 < 9) ? 0.f : -1e30f;

  int jcur  = blockIdx.x;        // first job static (GRID <= NJOBS)
  int bs    = jcur / 3;
  int mBase = (jcur - 3 * bs) * MH;
  const float* qb = query   + (size_t)bs * WWC;
  const float* sb = support + (size_t)bs * WWC;

  float wA[16];                  // in-flight A gather (issued 1 phase early)
  uint4 pg0, pg1; float pinv;    // staged-chunk payload across a barrier

  // ---- prologue: direct-stage c0(j0); put c1(j0) + af(j0) in flight ----
  {
    float v0[16];
    issue16(v0, qb + r, true, c16);               // rows 0..127 all valid
    uint4 g0, g1; float inv;
    conv16(v0, g0, g1, inv, true);
    writeP(&Qr[0][r * CCH], &iQr[0][r], g0, g1, inv, r, c16);
    float v1[16];
    issue16(v1, qb + QCH + r, true, c16);         // rows 128..255 all valid
    issueAF(wA, sb + mBase + am, (mBase + am) < WW, quad);
    blockbar();
    conv16(v1, pg0, pg1, pinv, true);             // af stays in flight
  }

  for (;;) {
    // ===== phase 0: compute c0(t); c1(t) write; c2(t) issue =====
    if (tid == 0) jslot = (int)(GRID + atomicAdd(ctr, 1u));
    writeP(&Qr[1][r * CCH], &iQr[1][r], pg0, pg1, pinv, r, c16);
    blockbar();
    const int  jn = __builtin_amdgcn_readfirstlane(jslot);
    const bool vn = jn < NJOBS;
    const int  jv  = vn ? jn : 0;
    const int  bsn = jv / 3;
    const int  mBn = (jv - 3 * bsn) * MH;
    const float* qbn = query   + (size_t)bsn * WWC;
    const float* sbn = support + (size_t)bsn * WWC;

    float vq[16];
    const bool v2 = (2 * QCH + r) < WW;           // chunk2 valid rows
    issue16(vq, qb + 2 * QCH + r, v2, c16);       // c2(t) in flight
    short8 af0, af1; float invA;
    afbuild(wA, (mBase + am) < WW, af0, af1, invA);
    f32x4 mx = {-3e38f, -3e38f, -3e38f, -3e38f};
    chunkCompute<8, false>(&Qr[0][0], &iQr[0][0], af0, af1,
                           boff0, boff1, l15, 0.f, mx);
    conv16(vq, pg0, pg1, pinv, v2);

    // ===== phase 1: compute c1(t); c2(t) write; c0(t+1) issue =====
    writeP(&Qr[2][r * CCH], &iQr[2][r], pg0, pg1, pinv, r, c16);
    blockbar();
    if (vn) issue16(vq, qbn + r, true, c16);      // c0(t+1)
    chunkCompute<8, false>(&Qr[1][0], &iQr[1][0], af0, af1,
                           boff0, boff1, l15, 0.f, mx);
    if (vn) conv16(vq, pg0, pg1, pinv, true);

    // ===== phase 2: compute c2(t) [7 tiles]; c0(t+1) write; c1(t+1)+af issue =====
    if (vn) writeP(&Qr[0][r * CCH], &iQr[0][r], pg0, pg1, pinv, r, c16);
    blockbar();
    if (vn) {
      issue16(vq, qbn + QCH + r, true, c16);      // c1(t+1)
      issueAF(wA, sbn + mBn + am, (mBn + am) < WW, quad);
    }
    // rows 368..383 are pure pad -> tile 7 skipped entirely; bias on tile 6
    chunkCompute<7, true>(&Qr[2][0], &iQr[2][0], af0, af1,
                          boff0, boff1, l15, lastbias, mx);

    // epilogue: max over columns (C layout: col = lane&15), then store
    #pragma unroll
    for (int d = 1; d < 16; d <<= 1) {
      #pragma unroll
      for (int rr = 0; rr < 4; ++rr) mx[rr] = fmaxf(mx[rr], __shfl_xor(mx[rr], d));
    }
    {
      const float iv0 = __shfl(invA, 4 * quad + 0);
      const float iv1 = __shfl(invA, 4 * quad + 1);
      const float iv2 = __shfl(invA, 4 * quad + 2);
      const float iv3 = __shfl(invA, 4 * quad + 3);
      if (l15 == 0) {
        const size_t ob = (size_t)bs * WW;
        const int mL = 16 * wv + 4 * quad;
        if (mBase + mL + 0 < WW) out[ob + mBase + mL + 0] = mx[0] * iv0;
        if (mBase + mL + 1 < WW) out[ob + mBase + mL + 1] = mx[1] * iv1;
        if (mBase + mL + 2 < WW) out[ob + mBase + mL + 2] = mx[2] * iv2;
        if (mBase + mL + 3 < WW) out[ob + mBase + mL + 3] = mx[3] * iv3;
      }
    }

    if (!vn) break;
    conv16(vq, pg0, pg1, pinv, true);             // af(t+1) stays in flight

    jcur = jn; bs = bsn; mBase = mBn; qb = qbn; sb = sbn;
  }
}

extern "C" void kernel_launch(void* const* d_in, const int* in_sizes, int n_in,
                              void* d_out, int out_size, void* d_ws, size_t ws_size,
                              hipStream_t stream) {
  const float* support = (const float*)d_in[0];
  const float* query   = (const float*)d_in[1];
  float* out = (float*)d_out;
  unsigned int* ctr = (unsigned int*)d_ws;
  hipMemsetAsync(ctr, 0, sizeof(unsigned int), stream);  // reset per replay
  dim3 grid(GRID), block(NTHR);
  hipLaunchKernelGGL(cossim_max_kernel, grid, block, 0, stream,
                     support, query, out, ctr);
}